// Round 1
// baseline (1554.924 us; speedup 1.0000x reference)
//
#include <hip/hip_runtime.h>
#include <hip/hip_bf16.h>

// Problem constants (fixed by the reference)
#define NNODES 50000
#define NREL   20
#define NSEG   (NNODES * NREL)   // 1,000,000
#define DEMB   64
#define DHID   128

// ---------------------------------------------------------------------------
// CSR build: histogram -> exclusive scan (3 kernels) -> placement
// ---------------------------------------------------------------------------

__global__ void hist_kernel(const int* __restrict__ dst, const int* __restrict__ et,
                            int E, int* __restrict__ cnt) {
    for (int e = blockIdx.x * blockDim.x + threadIdx.x; e < E; e += gridDim.x * blockDim.x) {
        atomicAdd(&cnt[dst[e] * NREL + et[e]], 1);
    }
}

// partial sums over chunks of 1024
__global__ void scan_partial(const int* __restrict__ cnt, int* __restrict__ bsum, int n) {
    __shared__ int s[256];
    int base = blockIdx.x * 1024;
    int t = threadIdx.x;
    int v = 0;
    for (int i = t; i < 1024; i += 256) {
        int idx = base + i;
        v += (idx < n) ? cnt[idx] : 0;
    }
    s[t] = v;
    __syncthreads();
    for (int o = 128; o > 0; o >>= 1) {
        if (t < o) s[t] += s[t + o];
        __syncthreads();
    }
    if (t == 0) bsum[blockIdx.x] = s[0];
}

// exclusive scan of block sums (nb <= 1024), in place
__global__ void scan_bsums(int* __restrict__ bsum, int nb) {
    __shared__ int s[1024];
    int t = threadIdx.x;
    s[t] = (t < nb) ? bsum[t] : 0;
    __syncthreads();
    for (int o = 1; o < 1024; o <<= 1) {
        int v = (t >= o) ? s[t - o] : 0;
        __syncthreads();
        s[t] += v;
        __syncthreads();
    }
    if (t < nb) bsum[t] = (t == 0) ? 0 : s[t - 1];
}

// final exclusive offsets: off[i] = exclusive_scan(cnt)[i]
__global__ void scan_final(const int* __restrict__ cnt, const int* __restrict__ bsum,
                           int* __restrict__ off, int n) {
    __shared__ int s[256];
    int base = blockIdx.x * 1024;
    int t = threadIdx.x;
    int idx = base + t * 4;
    int a0 = (idx + 0 < n) ? cnt[idx + 0] : 0;
    int a1 = (idx + 1 < n) ? cnt[idx + 1] : 0;
    int a2 = (idx + 2 < n) ? cnt[idx + 2] : 0;
    int a3 = (idx + 3 < n) ? cnt[idx + 3] : 0;
    s[t] = a0 + a1 + a2 + a3;
    __syncthreads();
    for (int o = 1; o < 256; o <<= 1) {
        int v = (t >= o) ? s[t - o] : 0;
        __syncthreads();
        s[t] += v;
        __syncthreads();
    }
    int base_ex = ((t == 0) ? 0 : s[t - 1]) + bsum[blockIdx.x];
    if (idx + 0 < n) off[idx + 0] = base_ex;
    if (idx + 1 < n) off[idx + 1] = base_ex + a0;
    if (idx + 2 < n) off[idx + 2] = base_ex + a0 + a1;
    if (idx + 3 < n) off[idx + 3] = base_ex + a0 + a1 + a2;
}

// placement: off[seg] is mutated from start -> end (atomicAdd returns slot)
__global__ void place_kernel(const int* __restrict__ src, const int* __restrict__ dst,
                             const int* __restrict__ et, int E,
                             int* __restrict__ off_mut, int* __restrict__ csr_src) {
    for (int e = blockIdx.x * blockDim.x + threadIdx.x; e < E; e += gridDim.x * blockDim.x) {
        int seg = dst[e] * NREL + et[e];
        int p = atomicAdd(&off_mut[seg], 1);
        csr_src[p] = src[e];
    }
}

// ---------------------------------------------------------------------------
// Fused RGCN layer: per block of 32 nodes, loop 20 relations + root:
//   gather segment-mean into LDS, then mini-GEMM into register accumulators.
// off[] holds segment ENDS (post-placement); start = end - cnt.
// ---------------------------------------------------------------------------

template <int K, bool RELU>
__global__ __launch_bounds__(256) void rgcn_layer_kernel(
    const float* __restrict__ X,     // [N][K]
    const float* __restrict__ W,     // [NREL][K][128]
    const float* __restrict__ root,  // [K][128]
    const float* __restrict__ bias,  // [128]
    const int* __restrict__ off,     // [NSEG] segment ends
    const int* __restrict__ cnt,     // [NSEG]
    const int* __restrict__ csr_src, // [E]
    float* __restrict__ H,           // [N][128]
    int nnodes)
{
    constexpr int NB = 32;
    constexpr int KP = K + 4;            // pad to spread LDS banks across teams
    __shared__ float meanS[NB * KP];

    const int n0 = blockIdx.x * NB;
    const int t  = threadIdx.x;

    // GEMM mapping: 32 col-groups (4 cols) x 8 node-groups (4 nodes)
    const int cg = t & 31;
    const int ng = t >> 5;
    const int c0 = cg * 4;

    // gather mapping: 32 teams (1 node each) x 8 lanes
    const int team  = t >> 3;
    const int lane8 = t & 7;

    float acc[4][4];
    {
        const float4 bv = *(const float4*)&bias[c0];
        #pragma unroll
        for (int i = 0; i < 4; ++i) {
            acc[i][0] = bv.x; acc[i][1] = bv.y; acc[i][2] = bv.z; acc[i][3] = bv.w;
        }
    }

    for (int rr = 0; rr <= NREL; ++rr) {
        __syncthreads();   // protect previous GEMM reads before overwriting meanS
        if (rr < NREL) {
            // zero
            for (int i = t; i < NB * KP; i += 256) meanS[i] = 0.0f;
            __syncthreads();
            // gather-sum x[src] for this block's 32 segments of relation rr
            const int n = n0 + team;
            if (n < nnodes) {
                const int seg  = n * NREL + rr;
                const int send = off[seg];
                const int c    = cnt[seg];
                const int s0   = send - c;
                float* mrow = &meanS[team * KP];
                for (int j = 0; j < c; ++j) {
                    const int s = csr_src[s0 + j];
                    const float* xr = X + (size_t)s * K;
                    #pragma unroll
                    for (int q = 0; q < K / 32; ++q) {
                        const int k4 = lane8 + q * 8;        // float4 index
                        const float4 v = *(const float4*)&xr[k4 * 4];
                        float4 m = *(float4*)&mrow[k4 * 4];
                        m.x += v.x; m.y += v.y; m.z += v.z; m.w += v.w;
                        *(float4*)&mrow[k4 * 4] = m;
                    }
                }
            }
            __syncthreads();
            // mean = sum / max(cnt,1)  (true IEEE division, matches reference)
            for (int i = t; i < NB * K; i += 256) {
                const int node = i / K;
                const int k    = i % K;
                const int nn   = n0 + node;
                if (nn < nnodes) {
                    const int c = cnt[nn * NREL + rr];
                    if (c > 1) meanS[node * KP + k] /= (float)c;
                }
            }
            __syncthreads();
        } else {
            // root pseudo-relation: meanS[node][k] = X[n][k]
            for (int i = t; i < NB * K; i += 256) {
                const int node = i / K;
                const int k    = i % K;
                const int nn   = n0 + node;
                meanS[node * KP + k] = (nn < nnodes) ? X[(size_t)nn * K + k] : 0.0f;
            }
            __syncthreads();
        }

        const float* Wr = (rr < NREL) ? (W + (size_t)rr * K * 128) : root;
        // acc[i][j] += sum_k meanS[ng*4+i][k] * Wr[k][c0+j]
        #pragma unroll 4
        for (int k = 0; k < K; ++k) {
            const float4 w = *(const float4*)&Wr[k * 128 + c0];
            #pragma unroll
            for (int i = 0; i < 4; ++i) {
                const float m = meanS[(ng * 4 + i) * KP + k];
                acc[i][0] += m * w.x;
                acc[i][1] += m * w.y;
                acc[i][2] += m * w.z;
                acc[i][3] += m * w.w;
            }
        }
    }

    // write H
    #pragma unroll
    for (int i = 0; i < 4; ++i) {
        const int n = n0 + ng * 4 + i;
        if (n < nnodes) {
            float4 o;
            o.x = RELU ? fmaxf(acc[i][0], 0.0f) : acc[i][0];
            o.y = RELU ? fmaxf(acc[i][1], 0.0f) : acc[i][1];
            o.z = RELU ? fmaxf(acc[i][2], 0.0f) : acc[i][2];
            o.w = RELU ? fmaxf(acc[i][3], 0.0f) : acc[i][3];
            *(float4*)&H[(size_t)n * 128 + c0] = o;
        }
    }
}

// ---------------------------------------------------------------------------
// DistMult decoder: one 64-lane wave per batch element
// ---------------------------------------------------------------------------
__global__ void decoder_kernel(const float* __restrict__ H, const float* __restrict__ rel_emb,
                               const int* __restrict__ head, const int* __restrict__ tail,
                               const int* __restrict__ rt, float* __restrict__ out, int B) {
    const int idx  = blockIdx.x * blockDim.x + threadIdx.x;
    const int b    = idx >> 6;
    const int lane = idx & 63;
    if (b >= B) return;
    const float* hp = H + (size_t)head[b] * 128;
    const float* tp = H + (size_t)tail[b] * 128;
    const float* rp = rel_emb + (size_t)rt[b] * 128;
    double s = 0.0;
    #pragma unroll
    for (int c = 0; c < 2; ++c) {
        const int k = lane + c * 64;
        s += (double)hp[k] * (double)rp[k] * (double)tp[k];
    }
    for (int o = 32; o > 0; o >>= 1) s += __shfl_down(s, o);
    if (lane == 0) out[b] = (float)s;
}

// ---------------------------------------------------------------------------

extern "C" void kernel_launch(void* const* d_in, const int* in_sizes, int n_in,
                              void* d_out, int out_size, void* d_ws, size_t ws_size,
                              hipStream_t stream) {
    const int*   edge_index = (const int*)d_in[0];   // [2][E]
    const int*   edge_type  = (const int*)d_in[1];   // [E]
    const int*   head       = (const int*)d_in[2];   // [B]
    const int*   tail       = (const int*)d_in[3];   // [B]
    const int*   rtyp       = (const int*)d_in[4];   // [B]
    const float* node_emb   = (const float*)d_in[5]; // [N][64]
    const float* W1         = (const float*)d_in[6]; // [20][64][128]
    const float* root1      = (const float*)d_in[7]; // [64][128]
    const float* b1         = (const float*)d_in[8]; // [128]
    const float* W2         = (const float*)d_in[9]; // [20][128][128]
    const float* root2      = (const float*)d_in[10];// [128][128]
    const float* b2         = (const float*)d_in[11];// [128]
    const float* rel_emb    = (const float*)d_in[12];// [20][128]
    float* out = (float*)d_out;

    const int E = in_sizes[1];
    const int B = in_sizes[2];
    const int* src = edge_index;
    const int* dst = edge_index + E;

    // workspace carve (all 256B-aligned)
    char* ws = (char*)d_ws;
    size_t o = 0;
    auto carve = [&](size_t bytes) { char* p = ws + o; o += (bytes + 255) & ~size_t(255); return p; };
    int*   off     = (int*)carve(sizeof(int) * NSEG);        // 4 MB
    int*   cnt     = (int*)carve(sizeof(int) * NSEG);        // 4 MB
    int*   csr_src = (int*)carve(sizeof(int) * (size_t)E);   // 6.4 MB
    int*   bsum    = (int*)carve(sizeof(int) * 1024);
    float* h1      = (float*)carve(sizeof(float) * (size_t)NNODES * DHID); // 25.6 MB
    float* h2      = (float*)carve(sizeof(float) * (size_t)NNODES * DHID); // 25.6 MB
    (void)ws_size;

    const int NCHUNK = (NSEG + 1023) / 1024;   // 977

    // CSR build
    hipMemsetAsync(cnt, 0, sizeof(int) * NSEG, stream);
    hist_kernel<<<2048, 256, 0, stream>>>(dst, edge_type, E, cnt);
    scan_partial<<<NCHUNK, 256, 0, stream>>>(cnt, bsum, NSEG);
    scan_bsums<<<1, 1024, 0, stream>>>(bsum, NCHUNK);
    scan_final<<<NCHUNK, 256, 0, stream>>>(cnt, bsum, off, NSEG);
    place_kernel<<<2048, 256, 0, stream>>>(src, dst, edge_type, E, off, csr_src);

    // layers
    const int LBLK = (NNODES + 31) / 32;   // 1563
    rgcn_layer_kernel<DEMB, true ><<<LBLK, 256, 0, stream>>>(node_emb, W1, root1, b1,
                                                             off, cnt, csr_src, h1, NNODES);
    rgcn_layer_kernel<DHID, false><<<LBLK, 256, 0, stream>>>(h1, W2, root2, b2,
                                                             off, cnt, csr_src, h2, NNODES);

    // decoder
    decoder_kernel<<<(B * 64 + 255) / 256, 256, 0, stream>>>(h2, rel_emb, head, tail, rtyp, out, B);
}

// Round 2
// 1165.249 us; speedup vs baseline: 1.3344x; 1.3344x over previous
//
#include <hip/hip_runtime.h>
#include <hip/hip_bf16.h>

// Problem constants (fixed by the reference)
#define NNODES 50000
#define NREL   20
#define NSEG   (NNODES * NREL)   // 1,000,000
#define DEMB   64
#define DHID   128

// ---------------------------------------------------------------------------
// CSR build: histogram -> exclusive scan (3 kernels) -> placement
// ---------------------------------------------------------------------------

__global__ void hist_kernel(const int* __restrict__ dst, const int* __restrict__ et,
                            int E, int* __restrict__ cnt) {
    for (int e = blockIdx.x * blockDim.x + threadIdx.x; e < E; e += gridDim.x * blockDim.x) {
        atomicAdd(&cnt[dst[e] * NREL + et[e]], 1);
    }
}

__global__ void scan_partial(const int* __restrict__ cnt, int* __restrict__ bsum, int n) {
    __shared__ int s[256];
    int base = blockIdx.x * 1024;
    int t = threadIdx.x;
    int v = 0;
    for (int i = t; i < 1024; i += 256) {
        int idx = base + i;
        v += (idx < n) ? cnt[idx] : 0;
    }
    s[t] = v;
    __syncthreads();
    for (int o = 128; o > 0; o >>= 1) {
        if (t < o) s[t] += s[t + o];
        __syncthreads();
    }
    if (t == 0) bsum[blockIdx.x] = s[0];
}

__global__ void scan_bsums(int* __restrict__ bsum, int nb) {
    __shared__ int s[1024];
    int t = threadIdx.x;
    s[t] = (t < nb) ? bsum[t] : 0;
    __syncthreads();
    for (int o = 1; o < 1024; o <<= 1) {
        int v = (t >= o) ? s[t - o] : 0;
        __syncthreads();
        s[t] += v;
        __syncthreads();
    }
    if (t < nb) bsum[t] = (t == 0) ? 0 : s[t - 1];
}

__global__ void scan_final(const int* __restrict__ cnt, const int* __restrict__ bsum,
                           int* __restrict__ off, int n) {
    __shared__ int s[256];
    int base = blockIdx.x * 1024;
    int t = threadIdx.x;
    int idx = base + t * 4;
    int a0 = (idx + 0 < n) ? cnt[idx + 0] : 0;
    int a1 = (idx + 1 < n) ? cnt[idx + 1] : 0;
    int a2 = (idx + 2 < n) ? cnt[idx + 2] : 0;
    int a3 = (idx + 3 < n) ? cnt[idx + 3] : 0;
    s[t] = a0 + a1 + a2 + a3;
    __syncthreads();
    for (int o = 1; o < 256; o <<= 1) {
        int v = (t >= o) ? s[t - o] : 0;
        __syncthreads();
        s[t] += v;
        __syncthreads();
    }
    int base_ex = ((t == 0) ? 0 : s[t - 1]) + bsum[blockIdx.x];
    if (idx + 0 < n) off[idx + 0] = base_ex;
    if (idx + 1 < n) off[idx + 1] = base_ex + a0;
    if (idx + 2 < n) off[idx + 2] = base_ex + a0 + a1;
    if (idx + 3 < n) off[idx + 3] = base_ex + a0 + a1 + a2;
}

// placement: off[seg] is mutated from start -> end (atomicAdd returns slot)
__global__ void place_kernel(const int* __restrict__ src, const int* __restrict__ dst,
                             const int* __restrict__ et, int E,
                             int* __restrict__ off_mut, int* __restrict__ csr_src) {
    for (int e = blockIdx.x * blockDim.x + threadIdx.x; e < E; e += gridDim.x * blockDim.x) {
        int seg = dst[e] * NREL + et[e];
        int p = atomicAdd(&off_mut[seg], 1);
        csr_src[p] = src[e];
    }
}

// ---------------------------------------------------------------------------
// Fused RGCN layer v2.
//  NB=64 nodes/block, 512 threads. Per relation (+root pseudo-relation):
//   - W_r chunk staged into LDS via global_load_lds (issued before gather,
//     HBM latency hides under the gather phase)
//   - gather segment-sum in REGISTERS (8 lanes/node), divide once, one
//     float4 store into pad-8 LDS layout
//   - register-tiled GEMM: 4 nodes x 4 cols/thread, k-unrolled x4:
//     8 ds_read_b128 per 64 v_fma_f32
// ---------------------------------------------------------------------------

__device__ __forceinline__ void load_lds16(const float* g, float* l) {
    __builtin_amdgcn_global_load_lds(
        (const __attribute__((address_space(1))) void*)g,
        (__attribute__((address_space(3))) void*)l, 16, 0, 0);
}

template <int K, bool RELU>
__global__ __launch_bounds__(512, 4) void rgcn_layer_kernel(
    const float* __restrict__ X,     // [N][K]
    const float* __restrict__ W,     // [NREL][K][128]
    const float* __restrict__ root,  // [K][128]
    const float* __restrict__ bias,  // [128]
    const int* __restrict__ off,     // [NSEG] segment ends
    const int* __restrict__ cnt,     // [NSEG]
    const int* __restrict__ csr_src, // [E]
    float* __restrict__ H,           // [N][128]
    int nnodes)
{
    constexpr int NB = 64;
    constexpr int KP = K + 8;        // pad 8: 2-way (free) conflicts on stores
    constexpr int KC = 64;           // W chunk rows
    constexpr int NCH = K / KC;      // chunks per relation (1 or 2)

    __shared__ float meanS[NB * KP];
    __shared__ float Wbuf[KC * 128];
    __shared__ int   cntS[NB * NREL];
    __shared__ int   offS[NB * NREL];

    const int n0 = blockIdx.x * NB;
    const int t  = threadIdx.x;

    // GEMM mapping: 32 col-groups (4 cols) x 16 node-groups (4 nodes)
    const int cg  = t & 31;
    const int ng4 = (t >> 5) * 4;
    const int c0  = cg * 4;

    // gather mapping: 64 teams (1 node each) x 8 lanes
    const int team  = t >> 3;
    const int lane8 = t & 7;

    // preload this block's cnt/off (coalesced: segs are contiguous per block)
    {
        const int nv  = min(NB, nnodes - n0);
        const int tot = nv * NREL;
        const int base = n0 * NREL;
        for (int i = t; i < tot; i += 512) {
            cntS[i] = cnt[base + i];
            offS[i] = off[base + i];
        }
    }

    float acc[4][4];
    {
        const float4 bv = *(const float4*)&bias[c0];
        #pragma unroll
        for (int i = 0; i < 4; ++i) {
            acc[i][0] = bv.x; acc[i][1] = bv.y; acc[i][2] = bv.z; acc[i][3] = bv.w;
        }
    }

    for (int rr = 0; rr <= NREL; ++rr) {
        __syncthreads();   // prev GEMM done with meanS/Wbuf; (rr=0: preload visible)

        const float* Wr = (rr < NREL) ? (W + (size_t)rr * K * 128) : root;

        // ---- issue W chunk 0 stage (async; lands under the gather) ----
        {
            const int wid  = t >> 6;
            const int lane = t & 63;
            #pragma unroll
            for (int u = 0; u < 4; ++u) {              // 8 waves x 4 x 1KB = 32KB
                const int ci = wid * 4 + u;
                load_lds16(Wr + ci * 256 + lane * 4, Wbuf + ci * 256);
            }
        }

        // ---- gather segment-mean into registers, store to meanS ----
        {
            const int n = n0 + team;
            if (n < nnodes) {
                float4 s[K / 32];
                #pragma unroll
                for (int q = 0; q < K / 32; ++q) s[q] = make_float4(0.f, 0.f, 0.f, 0.f);

                if (rr < NREL) {
                    const int c  = cntS[team * NREL + rr];
                    const int s0 = offS[team * NREL + rr] - c;
                    for (int j = 0; j < c; ++j) {
                        const int sv = csr_src[s0 + j];
                        const float* xr = X + (size_t)sv * K;
                        #pragma unroll
                        for (int q = 0; q < K / 32; ++q) {
                            const float4 v = *(const float4*)&xr[(lane8 + q * 8) * 4];
                            s[q].x += v.x; s[q].y += v.y; s[q].z += v.z; s[q].w += v.w;
                        }
                    }
                    const float inv = 1.0f / (float)max(c, 1);
                    #pragma unroll
                    for (int q = 0; q < K / 32; ++q) {
                        s[q].x *= inv; s[q].y *= inv; s[q].z *= inv; s[q].w *= inv;
                    }
                } else {
                    const float* xr = X + (size_t)n * K;
                    #pragma unroll
                    for (int q = 0; q < K / 32; ++q)
                        s[q] = *(const float4*)&xr[(lane8 + q * 8) * 4];
                }
                #pragma unroll
                for (int q = 0; q < K / 32; ++q)
                    *(float4*)&meanS[team * KP + (lane8 + q * 8) * 4] = s[q];
            }
        }

        // ---- GEMM over W chunks ----
        #pragma unroll
        for (int kc = 0; kc < NCH; ++kc) {
            __syncthreads();   // drains vmcnt: Wbuf chunk kc landed; meanS ready

            #pragma unroll 2
            for (int k0 = 0; k0 < KC; k0 += 4) {
                const int ka = kc * KC + k0;
                const float4 w0 = *(const float4*)&Wbuf[(k0 + 0) * 128 + c0];
                const float4 w1 = *(const float4*)&Wbuf[(k0 + 1) * 128 + c0];
                const float4 w2 = *(const float4*)&Wbuf[(k0 + 2) * 128 + c0];
                const float4 w3 = *(const float4*)&Wbuf[(k0 + 3) * 128 + c0];
                #pragma unroll
                for (int i = 0; i < 4; ++i) {
                    const float4 m = *(const float4*)&meanS[(ng4 + i) * KP + ka];
                    acc[i][0] = fmaf(m.w, w3.x, fmaf(m.z, w2.x, fmaf(m.y, w1.x, fmaf(m.x, w0.x, acc[i][0]))));
                    acc[i][1] = fmaf(m.w, w3.y, fmaf(m.z, w2.y, fmaf(m.y, w1.y, fmaf(m.x, w0.y, acc[i][1]))));
                    acc[i][2] = fmaf(m.w, w3.z, fmaf(m.z, w2.z, fmaf(m.y, w1.z, fmaf(m.x, w0.z, acc[i][2]))));
                    acc[i][3] = fmaf(m.w, w3.w, fmaf(m.z, w2.w, fmaf(m.y, w1.w, fmaf(m.x, w0.w, acc[i][3]))));
                }
            }

            if (kc + 1 < NCH) {
                __syncthreads();   // all waves done reading Wbuf chunk kc
                const int wid  = t >> 6;
                const int lane = t & 63;
                const float* Wc = Wr + (size_t)(kc + 1) * KC * 128;
                #pragma unroll
                for (int u = 0; u < 4; ++u) {
                    const int ci = wid * 4 + u;
                    load_lds16(Wc + ci * 256 + lane * 4, Wbuf + ci * 256);
                }
            }
        }
    }

    // write H
    #pragma unroll
    for (int i = 0; i < 4; ++i) {
        const int n = n0 + ng4 + i;
        if (n < nnodes) {
            float4 o;
            o.x = RELU ? fmaxf(acc[i][0], 0.0f) : acc[i][0];
            o.y = RELU ? fmaxf(acc[i][1], 0.0f) : acc[i][1];
            o.z = RELU ? fmaxf(acc[i][2], 0.0f) : acc[i][2];
            o.w = RELU ? fmaxf(acc[i][3], 0.0f) : acc[i][3];
            *(float4*)&H[(size_t)n * 128 + c0] = o;
        }
    }
}

// ---------------------------------------------------------------------------
// DistMult decoder: one 64-lane wave per batch element
// ---------------------------------------------------------------------------
__global__ void decoder_kernel(const float* __restrict__ H, const float* __restrict__ rel_emb,
                               const int* __restrict__ head, const int* __restrict__ tail,
                               const int* __restrict__ rt, float* __restrict__ out, int B) {
    const int idx  = blockIdx.x * blockDim.x + threadIdx.x;
    const int b    = idx >> 6;
    const int lane = idx & 63;
    if (b >= B) return;
    const float* hp = H + (size_t)head[b] * 128;
    const float* tp = H + (size_t)tail[b] * 128;
    const float* rp = rel_emb + (size_t)rt[b] * 128;
    double s = 0.0;
    #pragma unroll
    for (int c = 0; c < 2; ++c) {
        const int k = lane + c * 64;
        s += (double)hp[k] * (double)rp[k] * (double)tp[k];
    }
    for (int o = 32; o > 0; o >>= 1) s += __shfl_down(s, o);
    if (lane == 0) out[b] = (float)s;
}

// ---------------------------------------------------------------------------

extern "C" void kernel_launch(void* const* d_in, const int* in_sizes, int n_in,
                              void* d_out, int out_size, void* d_ws, size_t ws_size,
                              hipStream_t stream) {
    const int*   edge_index = (const int*)d_in[0];   // [2][E]
    const int*   edge_type  = (const int*)d_in[1];   // [E]
    const int*   head       = (const int*)d_in[2];   // [B]
    const int*   tail       = (const int*)d_in[3];   // [B]
    const int*   rtyp       = (const int*)d_in[4];   // [B]
    const float* node_emb   = (const float*)d_in[5]; // [N][64]
    const float* W1         = (const float*)d_in[6]; // [20][64][128]
    const float* root1      = (const float*)d_in[7]; // [64][128]
    const float* b1         = (const float*)d_in[8]; // [128]
    const float* W2         = (const float*)d_in[9]; // [20][128][128]
    const float* root2      = (const float*)d_in[10];// [128][128]
    const float* b2         = (const float*)d_in[11];// [128]
    const float* rel_emb    = (const float*)d_in[12];// [20][128]
    float* out = (float*)d_out;

    const int E = in_sizes[1];
    const int B = in_sizes[2];
    const int* src = edge_index;
    const int* dst = edge_index + E;

    // workspace carve (all 256B-aligned)
    char* ws = (char*)d_ws;
    size_t o = 0;
    auto carve = [&](size_t bytes) { char* p = ws + o; o += (bytes + 255) & ~size_t(255); return p; };
    int*   off     = (int*)carve(sizeof(int) * NSEG);        // 4 MB
    int*   cnt     = (int*)carve(sizeof(int) * NSEG);        // 4 MB
    int*   csr_src = (int*)carve(sizeof(int) * (size_t)E);   // 6.4 MB
    int*   bsum    = (int*)carve(sizeof(int) * 1024);
    float* h1      = (float*)carve(sizeof(float) * (size_t)NNODES * DHID); // 25.6 MB
    float* h2      = (float*)carve(sizeof(float) * (size_t)NNODES * DHID); // 25.6 MB
    (void)ws_size;

    const int NCHUNK = (NSEG + 1023) / 1024;   // 977

    // CSR build
    hipMemsetAsync(cnt, 0, sizeof(int) * NSEG, stream);
    hist_kernel<<<2048, 256, 0, stream>>>(dst, edge_type, E, cnt);
    scan_partial<<<NCHUNK, 256, 0, stream>>>(cnt, bsum, NSEG);
    scan_bsums<<<1, 1024, 0, stream>>>(bsum, NCHUNK);
    scan_final<<<NCHUNK, 256, 0, stream>>>(cnt, bsum, off, NSEG);
    place_kernel<<<2048, 256, 0, stream>>>(src, dst, edge_type, E, off, csr_src);

    // layers (64 nodes per block, 512 threads)
    const int LBLK = (NNODES + 63) / 64;   // 782
    rgcn_layer_kernel<DEMB, true ><<<LBLK, 512, 0, stream>>>(node_emb, W1, root1, b1,
                                                             off, cnt, csr_src, h1, NNODES);
    rgcn_layer_kernel<DHID, false><<<LBLK, 512, 0, stream>>>(h1, W2, root2, b2,
                                                             off, cnt, csr_src, h2, NNODES);

    // decoder
    decoder_kernel<<<(B * 64 + 255) / 256, 256, 0, stream>>>(h2, rel_emb, head, tail, rtyp, out, B);
}

// Round 4
// 902.564 us; speedup vs baseline: 1.7228x; 1.2910x over previous
//
#include <hip/hip_runtime.h>
#include <hip/hip_bf16.h>

// Problem constants (fixed by the reference)
#define NNODES 50000
#define NREL   20
#define NSEG   (NNODES * NREL)   // 1,000,000
#define DEMB   64
#define DHID   128

typedef __attribute__((ext_vector_type(8))) short short8;
typedef __attribute__((ext_vector_type(4))) float f32x4;

__device__ __forceinline__ unsigned short bf16rn(float x) {
    unsigned u = __builtin_bit_cast(unsigned, x);
    unsigned r = u + 0x7FFFu + ((u >> 16) & 1u);
    return (unsigned short)(r >> 16);
}
__device__ __forceinline__ float bf16tof(unsigned short h) {
    return __builtin_bit_cast(float, (unsigned)h << 16);
}

// ---------------------------------------------------------------------------
// CSR build: histogram -> exclusive scan (3 kernels) -> placement
// ---------------------------------------------------------------------------

__global__ void hist_kernel(const int* __restrict__ dst, const int* __restrict__ et,
                            int E, int* __restrict__ cnt) {
    for (int e = blockIdx.x * blockDim.x + threadIdx.x; e < E; e += gridDim.x * blockDim.x) {
        atomicAdd(&cnt[dst[e] * NREL + et[e]], 1);
    }
}

__global__ void scan_partial(const int* __restrict__ cnt, int* __restrict__ bsum, int n) {
    __shared__ int s[256];
    int base = blockIdx.x * 1024;
    int t = threadIdx.x;
    int v = 0;
    for (int i = t; i < 1024; i += 256) {
        int idx = base + i;
        v += (idx < n) ? cnt[idx] : 0;
    }
    s[t] = v;
    __syncthreads();
    for (int o = 128; o > 0; o >>= 1) {
        if (t < o) s[t] += s[t + o];
        __syncthreads();
    }
    if (t == 0) bsum[blockIdx.x] = s[0];
}

__global__ void scan_bsums(int* __restrict__ bsum, int nb) {
    __shared__ int s[1024];
    int t = threadIdx.x;
    s[t] = (t < nb) ? bsum[t] : 0;
    __syncthreads();
    for (int o = 1; o < 1024; o <<= 1) {
        int v = (t >= o) ? s[t - o] : 0;
        __syncthreads();
        s[t] += v;
        __syncthreads();
    }
    if (t < nb) bsum[t] = (t == 0) ? 0 : s[t - 1];
}

__global__ void scan_final(const int* __restrict__ cnt, const int* __restrict__ bsum,
                           int* __restrict__ off, int n) {
    __shared__ int s[256];
    int base = blockIdx.x * 1024;
    int t = threadIdx.x;
    int idx = base + t * 4;
    int a0 = (idx + 0 < n) ? cnt[idx + 0] : 0;
    int a1 = (idx + 1 < n) ? cnt[idx + 1] : 0;
    int a2 = (idx + 2 < n) ? cnt[idx + 2] : 0;
    int a3 = (idx + 3 < n) ? cnt[idx + 3] : 0;
    s[t] = a0 + a1 + a2 + a3;
    __syncthreads();
    for (int o = 1; o < 256; o <<= 1) {
        int v = (t >= o) ? s[t - o] : 0;
        __syncthreads();
        s[t] += v;
        __syncthreads();
    }
    int base_ex = ((t == 0) ? 0 : s[t - 1]) + bsum[blockIdx.x];
    if (idx + 0 < n) off[idx + 0] = base_ex;
    if (idx + 1 < n) off[idx + 1] = base_ex + a0;
    if (idx + 2 < n) off[idx + 2] = base_ex + a0 + a1;
    if (idx + 3 < n) off[idx + 3] = base_ex + a0 + a1 + a2;
}

__global__ void place_kernel(const int* __restrict__ src, const int* __restrict__ dst,
                             const int* __restrict__ et, int E,
                             int* __restrict__ off_mut, int* __restrict__ csr_src) {
    for (int e = blockIdx.x * blockDim.x + threadIdx.x; e < E; e += gridDim.x * blockDim.x) {
        int seg = dst[e] * NREL + et[e];
        int p = atomicAdd(&off_mut[seg], 1);
        csr_src[p] = src[e];
    }
}

// ---------------------------------------------------------------------------
// W prep: split f32 W into (hi, lo) bf16 planes, transposed to [col][k],
// k-chunked by 32 with rows padded to 40 shorts (odd 16B-granule count ->
// conflict-free B-frag ds_read_b128).
// Wt layout (shorts): [rel 0..20][kchunk s][plane p][col c][40]
//   chunk stride = 10240 shorts (2 planes x 128 cols x 40)
// rel 20 == root.
// ---------------------------------------------------------------------------
template <int K>
__global__ void prep_w(const float* __restrict__ W, const float* __restrict__ root,
                       short* __restrict__ Wt) {
    constexpr int KS = K / 32;
    int idx = blockIdx.x * blockDim.x + threadIdx.x;
    int total = (NREL + 1) * 128 * K;
    if (idx >= total) return;
    int r   = idx / (128 * K);
    int rem = idx % (128 * K);
    int c   = rem / K;
    int k   = rem % K;
    float v = (r < NREL) ? W[((size_t)r * K + k) * 128 + c] : root[(size_t)k * 128 + c];
    unsigned short hi = bf16rn(v);
    unsigned short lo = bf16rn(v - bf16tof(hi));
    int s = k >> 5, kk = k & 31;
    size_t base = ((size_t)r * KS + s) * 10240 + (size_t)c * 40 + kk;
    Wt[base]        = (short)hi;
    Wt[base + 5120] = (short)lo;
}

// ---------------------------------------------------------------------------
// Fused RGCN layer v3 (MFMA bf16x3 split-product).
// NB=128 nodes/block, 512 threads (8 waves: 4 row-groups x 2 col-groups,
// each wave owns 32 nodes x 64 cols = 2x4 tiles of 16x16).
// Per relation (+root as rel 20): gather f32 segment-mean in registers,
// split to (hi,lo) bf16 planes in LDS; GEMM via mfma_f32_16x16x32_bf16:
// acc += a0*b0 + a0*b1 + a1*b0 (error ~2^-17, ~25x under threshold).
// ---------------------------------------------------------------------------

__device__ __forceinline__ void stage40(const short* __restrict__ gsrc,
                                        short* ldst, int t, int nbytes) {
    const int u = t >> 6, lane = t & 63;
    for (int j = 0; j < 8; ++j) {
        int blk = u + j * 8;
        if (blk * 1024 >= nbytes) break;
        __builtin_amdgcn_global_load_lds(
            (const __attribute__((address_space(1))) void*)((const char*)gsrc + blk * 1024 + lane * 16),
            (__attribute__((address_space(3))) void*)((char*)ldst + blk * 1024 + lane * 16),
            16, 0, 0);
    }
}

template <int K, bool RELU>
__global__ __launch_bounds__(512, (K == 64) ? 4 : 2) void rgcn_layer_kernel(
    const float* __restrict__ X,     // [N][K]
    const short* __restrict__ Wt,    // prepped split W (+root as rel 20)
    const float* __restrict__ bias,  // [128]
    const int* __restrict__ off,     // [NSEG] segment ends
    const int* __restrict__ cnt,     // [NSEG]
    const int* __restrict__ csr_src, // [E]
    float* __restrict__ H,           // [N][128]
    int nnodes)
{
    constexpr int NB  = 128;
    constexpr int KS  = K / 32;                 // k-steps of 32
    constexpr int NQ  = K / 32;                 // float4s per lane per edge row
    constexpr int RSs = (K == 128) ? 136 : 72;  // meanS row stride (shorts), odd granules
    constexpr int PS  = 128 * RSs;              // plane stride (shorts)

    __shared__ short meanS[2 * PS];
    __shared__ short Wbuf[20480];               // 40KB: 2 k-chunks of 20KB

    const int n0 = blockIdx.x * NB;
    const int t  = threadIdx.x;
    const int l  = t & 63;
    const int w  = t >> 6;
    const int rg = w & 3;        // row group: 32 nodes
    const int cg = w >> 2;       // col group: 64 cols

    // gather mapping: 64 teams of 8 lanes; each team handles nodes {team, team+64}
    const int team  = t >> 3;
    const int lane8 = t & 7;

    // accumulators: 2 row-tiles x 4 col-tiles of 16x16
    f32x4 acc[2][4];
    #pragma unroll
    for (int ct = 0; ct < 4; ++ct) {
        const float b = bias[cg * 64 + ct * 16 + (l & 15)];
        #pragma unroll
        for (int rt = 0; rt < 2; ++rt) acc[rt][ct] = (f32x4){b, b, b, b};
    }

    for (int rr = 0; rr <= NREL; ++rr) {
        __syncthreads();   // prev GEMM done reading meanS/Wbuf

        const short* wtRel = Wt + (size_t)rr * KS * 10240;

        // stage first (up to) 2 k-chunks of W; lands under the gather
        stage40(wtRel, Wbuf, t, (KS >= 2) ? 40960 : 20480);

        // ---- gather f32 segment-mean, split to bf16 planes in meanS ----
        #pragma unroll
        for (int sub = 0; sub < 2; ++sub) {
            const int nb   = team + 64 * sub;
            const int node = n0 + nb;
            if (node >= nnodes) continue;

            float sx[NQ], sy[NQ], sz[NQ], sw[NQ];
            #pragma unroll
            for (int q = 0; q < NQ; ++q) { sx[q] = 0.f; sy[q] = 0.f; sz[q] = 0.f; sw[q] = 0.f; }
            float inv = 1.0f;

            if (rr < NREL) {
                const int seg = node * NREL + rr;
                const int c   = cnt[seg];
                const int s0  = off[seg] - c;
                for (int j = 0; j < c; ++j) {
                    const int sv = csr_src[s0 + j];
                    const float* xr = X + (size_t)sv * K;
                    #pragma unroll
                    for (int q = 0; q < NQ; ++q) {
                        const float4 v = *(const float4*)&xr[q * 32 + lane8 * 4];
                        sx[q] += v.x; sy[q] += v.y; sz[q] += v.z; sw[q] += v.w;
                    }
                }
                inv = 1.0f / (float)max(c, 1);
            } else {
                const float* xr = X + (size_t)node * K;
                #pragma unroll
                for (int q = 0; q < NQ; ++q) {
                    const float4 v = *(const float4*)&xr[q * 32 + lane8 * 4];
                    sx[q] = v.x; sy[q] = v.y; sz[q] = v.z; sw[q] = v.w;
                }
            }

            #pragma unroll
            for (int q = 0; q < NQ; ++q) {
                const float vx = sx[q] * inv, vy = sy[q] * inv, vz = sz[q] * inv, vw = sw[q] * inv;
                const unsigned short hx = bf16rn(vx), hy = bf16rn(vy), hz = bf16rn(vz), hw = bf16rn(vw);
                short4 hi4, lo4;
                hi4.x = (short)hx; hi4.y = (short)hy; hi4.z = (short)hz; hi4.w = (short)hw;
                lo4.x = (short)bf16rn(vx - bf16tof(hx));
                lo4.y = (short)bf16rn(vy - bf16tof(hy));
                lo4.z = (short)bf16rn(vz - bf16tof(hz));
                lo4.w = (short)bf16rn(vw - bf16tof(hw));
                const int kbase = nb * RSs + q * 32 + lane8 * 4;
                *(short4*)&meanS[kbase]      = hi4;
                *(short4*)&meanS[PS + kbase] = lo4;
            }
        }

        asm volatile("s_waitcnt vmcnt(0)" ::: "memory");
        __syncthreads();

        // ---- GEMM: 3-product bf16 split MFMA ----
        #pragma unroll
        for (int s = 0; s < KS; ++s) {
            if (K == 128 && s == 2) {
                __syncthreads();                       // chunks 0,1 fully read
                stage40(wtRel + 2 * 10240, Wbuf, t, 40960);
                asm volatile("s_waitcnt vmcnt(0)" ::: "memory");
                __syncthreads();
            }
            const int half = (s & 1) * 10240;

            short8 bf[4][2];
            #pragma unroll
            for (int ct = 0; ct < 4; ++ct) {
                const int col = cg * 64 + ct * 16 + (l & 15);
                bf[ct][0] = *(const short8*)&Wbuf[half +        col * 40 + (l >> 4) * 8];
                bf[ct][1] = *(const short8*)&Wbuf[half + 5120 + col * 40 + (l >> 4) * 8];
            }

            #pragma unroll
            for (int rt = 0; rt < 2; ++rt) {
                const int row = rg * 32 + rt * 16 + (l & 15);
                const int ka  = row * RSs + s * 32 + (l >> 4) * 8;
                const short8 a0 = *(const short8*)&meanS[ka];
                const short8 a1 = *(const short8*)&meanS[PS + ka];
                #pragma unroll
                for (int ct = 0; ct < 4; ++ct) {
                    acc[rt][ct] = __builtin_amdgcn_mfma_f32_16x16x32_bf16(a0, bf[ct][0], acc[rt][ct], 0, 0, 0);
                    acc[rt][ct] = __builtin_amdgcn_mfma_f32_16x16x32_bf16(a0, bf[ct][1], acc[rt][ct], 0, 0, 0);
                    acc[rt][ct] = __builtin_amdgcn_mfma_f32_16x16x32_bf16(a1, bf[ct][0], acc[rt][ct], 0, 0, 0);
                }
            }
        }
    }

    // ---- write H: D layout col=lane&15, row=(lane>>4)*4+reg ----
    #pragma unroll
    for (int rt = 0; rt < 2; ++rt) {
        #pragma unroll
        for (int reg = 0; reg < 4; ++reg) {
            const int node = n0 + rg * 32 + rt * 16 + (l >> 4) * 4 + reg;
            if (node < nnodes) {
                #pragma unroll
                for (int ct = 0; ct < 4; ++ct) {
                    float v = acc[rt][ct][reg];
                    if (RELU) v = fmaxf(v, 0.0f);
                    H[(size_t)node * 128 + cg * 64 + ct * 16 + (l & 15)] = v;
                }
            }
        }
    }
}

// ---------------------------------------------------------------------------
// DistMult decoder: one 64-lane wave per batch element
// ---------------------------------------------------------------------------
__global__ void decoder_kernel(const float* __restrict__ H, const float* __restrict__ rel_emb,
                               const int* __restrict__ head, const int* __restrict__ tail,
                               const int* __restrict__ rt, float* __restrict__ out, int B) {
    const int idx  = blockIdx.x * blockDim.x + threadIdx.x;
    const int b    = idx >> 6;
    const int lane = idx & 63;
    if (b >= B) return;
    const float* hp = H + (size_t)head[b] * 128;
    const float* tp = H + (size_t)tail[b] * 128;
    const float* rp = rel_emb + (size_t)rt[b] * 128;
    double s = 0.0;
    #pragma unroll
    for (int c = 0; c < 2; ++c) {
        const int k = lane + c * 64;
        s += (double)hp[k] * (double)rp[k] * (double)tp[k];
    }
    for (int o = 32; o > 0; o >>= 1) s += __shfl_down(s, o);
    if (lane == 0) out[b] = (float)s;
}

// ---------------------------------------------------------------------------

extern "C" void kernel_launch(void* const* d_in, const int* in_sizes, int n_in,
                              void* d_out, int out_size, void* d_ws, size_t ws_size,
                              hipStream_t stream) {
    const int*   edge_index = (const int*)d_in[0];   // [2][E]
    const int*   edge_type  = (const int*)d_in[1];   // [E]
    const int*   head       = (const int*)d_in[2];   // [B]
    const int*   tail       = (const int*)d_in[3];   // [B]
    const int*   rtyp       = (const int*)d_in[4];   // [B]
    const float* node_emb   = (const float*)d_in[5]; // [N][64]
    const float* W1         = (const float*)d_in[6]; // [20][64][128]
    const float* root1      = (const float*)d_in[7]; // [64][128]
    const float* b1         = (const float*)d_in[8]; // [128]
    const float* W2         = (const float*)d_in[9]; // [20][128][128]
    const float* root2      = (const float*)d_in[10];// [128][128]
    const float* b2         = (const float*)d_in[11];// [128]
    const float* rel_emb    = (const float*)d_in[12];// [20][128]
    float* out = (float*)d_out;

    const int E = in_sizes[1];
    const int B = in_sizes[2];
    const int* src = edge_index;
    const int* dst = edge_index + E;

    // workspace carve (all 256B-aligned)
    char* ws = (char*)d_ws;
    size_t o = 0;
    auto carve = [&](size_t bytes) { char* p = ws + o; o += (bytes + 255) & ~size_t(255); return p; };
    int*   off     = (int*)carve(sizeof(int) * NSEG);        // 4 MB
    int*   cnt     = (int*)carve(sizeof(int) * NSEG);        // 4 MB
    int*   csr_src = (int*)carve(sizeof(int) * (size_t)E);   // 6.4 MB
    int*   bsum    = (int*)carve(sizeof(int) * 1024);
    float* h1      = (float*)carve(sizeof(float) * (size_t)NNODES * DHID); // 25.6 MB
    float* h2      = (float*)carve(sizeof(float) * (size_t)NNODES * DHID); // 25.6 MB
    short* Wt1     = (short*)carve(sizeof(short) * (size_t)(NREL + 1) * 2 * 10240); // 1.72 MB
    short* Wt2     = (short*)carve(sizeof(short) * (size_t)(NREL + 1) * 4 * 10240); // 3.44 MB
    (void)ws_size;

    const int NCHUNK = (NSEG + 1023) / 1024;   // 977

    // W prep (independent of CSR; cheap)
    {
        const int tot1 = (NREL + 1) * 128 * DEMB;
        const int tot2 = (NREL + 1) * 128 * DHID;
        prep_w<DEMB><<<(tot1 + 255) / 256, 256, 0, stream>>>(W1, root1, Wt1);
        prep_w<DHID><<<(tot2 + 255) / 256, 256, 0, stream>>>(W2, root2, Wt2);
    }

    // CSR build
    hipMemsetAsync(cnt, 0, sizeof(int) * NSEG, stream);
    hist_kernel<<<2048, 256, 0, stream>>>(dst, edge_type, E, cnt);
    scan_partial<<<NCHUNK, 256, 0, stream>>>(cnt, bsum, NSEG);
    scan_bsums<<<1, 1024, 0, stream>>>(bsum, NCHUNK);
    scan_final<<<NCHUNK, 256, 0, stream>>>(cnt, bsum, off, NSEG);
    place_kernel<<<2048, 256, 0, stream>>>(src, dst, edge_type, E, off, csr_src);

    // layers (128 nodes per block, 512 threads)
    const int LBLK = (NNODES + 127) / 128;   // 391
    rgcn_layer_kernel<DEMB, true ><<<LBLK, 512, 0, stream>>>(node_emb, Wt1, b1,
                                                             off, cnt, csr_src, h1, NNODES);
    rgcn_layer_kernel<DHID, false><<<LBLK, 512, 0, stream>>>(h1, Wt2, b2,
                                                             off, cnt, csr_src, h2, NNODES);

    // decoder
    decoder_kernel<<<(B * 64 + 255) / 256, 256, 0, stream>>>(h2, rel_emb, head, tail, rtyp, out, B);
}

// Round 5
// 731.998 us; speedup vs baseline: 2.1242x; 1.2330x over previous
//
#include <hip/hip_runtime.h>
#include <hip/hip_bf16.h>

// Problem constants (fixed by the reference)
#define NNODES 50000
#define NREL   20
#define NSEG   (NNODES * NREL)   // 1,000,000
#define DEMB   64
#define DHID   128

typedef __attribute__((ext_vector_type(8))) short short8;
typedef __attribute__((ext_vector_type(4))) float f32x4;

__device__ __forceinline__ unsigned short bf16rn(float x) {
    unsigned u = __builtin_bit_cast(unsigned, x);
    unsigned r = u + 0x7FFFu + ((u >> 16) & 1u);
    return (unsigned short)(r >> 16);
}
__device__ __forceinline__ float bf16tof(unsigned short h) {
    return __builtin_bit_cast(float, (unsigned)h << 16);
}

// ---------------------------------------------------------------------------
// CSR build: histogram -> exclusive scan (3 kernels) -> placement
// ---------------------------------------------------------------------------

__global__ void hist_kernel(const int* __restrict__ dst, const int* __restrict__ et,
                            int E, int* __restrict__ cnt) {
    for (int e = blockIdx.x * blockDim.x + threadIdx.x; e < E; e += gridDim.x * blockDim.x) {
        atomicAdd(&cnt[dst[e] * NREL + et[e]], 1);
    }
}

__global__ void scan_partial(const int* __restrict__ cnt, int* __restrict__ bsum, int n) {
    __shared__ int s[256];
    int base = blockIdx.x * 1024;
    int t = threadIdx.x;
    int v = 0;
    for (int i = t; i < 1024; i += 256) {
        int idx = base + i;
        v += (idx < n) ? cnt[idx] : 0;
    }
    s[t] = v;
    __syncthreads();
    for (int o = 128; o > 0; o >>= 1) {
        if (t < o) s[t] += s[t + o];
        __syncthreads();
    }
    if (t == 0) bsum[blockIdx.x] = s[0];
}

__global__ void scan_bsums(int* __restrict__ bsum, int nb) {
    __shared__ int s[1024];
    int t = threadIdx.x;
    s[t] = (t < nb) ? bsum[t] : 0;
    __syncthreads();
    for (int o = 1; o < 1024; o <<= 1) {
        int v = (t >= o) ? s[t - o] : 0;
        __syncthreads();
        s[t] += v;
        __syncthreads();
    }
    if (t < nb) bsum[t] = (t == 0) ? 0 : s[t - 1];
}

__global__ void scan_final(const int* __restrict__ cnt, const int* __restrict__ bsum,
                           int* __restrict__ off, int n) {
    __shared__ int s[256];
    int base = blockIdx.x * 1024;
    int t = threadIdx.x;
    int idx = base + t * 4;
    int a0 = (idx + 0 < n) ? cnt[idx + 0] : 0;
    int a1 = (idx + 1 < n) ? cnt[idx + 1] : 0;
    int a2 = (idx + 2 < n) ? cnt[idx + 2] : 0;
    int a3 = (idx + 3 < n) ? cnt[idx + 3] : 0;
    s[t] = a0 + a1 + a2 + a3;
    __syncthreads();
    for (int o = 1; o < 256; o <<= 1) {
        int v = (t >= o) ? s[t - o] : 0;
        __syncthreads();
        s[t] += v;
        __syncthreads();
    }
    int base_ex = ((t == 0) ? 0 : s[t - 1]) + bsum[blockIdx.x];
    if (idx + 0 < n) off[idx + 0] = base_ex;
    if (idx + 1 < n) off[idx + 1] = base_ex + a0;
    if (idx + 2 < n) off[idx + 2] = base_ex + a0 + a1;
    if (idx + 3 < n) off[idx + 3] = base_ex + a0 + a1 + a2;
}

__global__ void place_kernel(const int* __restrict__ src, const int* __restrict__ dst,
                             const int* __restrict__ et, int E,
                             int* __restrict__ off_mut, int* __restrict__ csr_src) {
    for (int e = blockIdx.x * blockDim.x + threadIdx.x; e < E; e += gridDim.x * blockDim.x) {
        int seg = dst[e] * NREL + et[e];
        int p = atomicAdd(&off_mut[seg], 1);
        csr_src[p] = src[e];
    }
}

// ---------------------------------------------------------------------------
// W prep: split f32 W into (hi, lo) bf16 planes, transposed to [col][k],
// k-chunked by 32 with rows padded to 40 shorts (5 granules/col, odd ->
// conflict-free B-frag ds_read_b128).
// Wt layout (shorts): [rel 0..20][kchunk s][plane p][col c][40]
//   chunk stride = 10240 shorts (2 planes x 128 cols x 40); rel 20 == root.
// ---------------------------------------------------------------------------
template <int K>
__global__ void prep_w(const float* __restrict__ W, const float* __restrict__ root,
                       short* __restrict__ Wt) {
    constexpr int KS = K / 32;
    int idx = blockIdx.x * blockDim.x + threadIdx.x;
    int total = (NREL + 1) * 128 * K;
    if (idx >= total) return;
    int r   = idx / (128 * K);
    int rem = idx % (128 * K);
    int c   = rem / K;
    int k   = rem % K;
    float v = (r < NREL) ? W[((size_t)r * K + k) * 128 + c] : root[(size_t)k * 128 + c];
    unsigned short hi = bf16rn(v);
    unsigned short lo = bf16rn(v - bf16tof(hi));
    int s = k >> 5, kk = k & 31;
    size_t base = ((size_t)r * KS + s) * 10240 + (size_t)c * 40 + kk;
    Wt[base]        = (short)hi;
    Wt[base + 5120] = (short)lo;
}

// ---------------------------------------------------------------------------
// Fused RGCN layer v4 (MFMA bf16x3, k-half phased LDS for 2 blocks/CU).
// NB=128 nodes/block, 512 threads (8 waves: 4 row-groups x 2 col-groups,
// each wave owns 32 nodes x 64 cols). Per relation (+root as rel 20):
//  - stage W chunks {0,1} async (lands under gather)
//  - fused dual-node branchless gather: full-K f32 sums in registers
//  - phase p in 0..K/64: write k-half p as (hi,lo) bf16 to meanS (36.8KB),
//    barrier (drains vmcnt), GEMM chunks {2p, 2p+1}; mid-rel re-stage for p=1
// LDS total 76KB -> 2 blocks/CU.
// ---------------------------------------------------------------------------

__device__ __forceinline__ void stage40(const short* __restrict__ gsrc,
                                        short* ldst, int t, int nbytes) {
    const int u = t >> 6, lane = t & 63;
    #pragma unroll
    for (int j = 0; j < 8; ++j) {
        int blk = u + j * 8;
        if (blk * 1024 >= nbytes) break;
        __builtin_amdgcn_global_load_lds(
            (const __attribute__((address_space(1))) void*)((const char*)gsrc + blk * 1024 + lane * 16),
            (__attribute__((address_space(3))) void*)((char*)ldst + blk * 1024 + lane * 16),
            16, 0, 0);
    }
}

template <int K, bool RELU>
__global__ __launch_bounds__(512, 4) void rgcn_layer_kernel(
    const float* __restrict__ X,     // [N][K]
    const short* __restrict__ Wt,    // prepped split W (+root as rel 20)
    const float* __restrict__ bias,  // [128]
    const int* __restrict__ off,     // [NSEG] segment ends
    const int* __restrict__ cnt,     // [NSEG]
    const int* __restrict__ csr_src, // [E]
    float* __restrict__ H,           // [N][128]
    int nnodes)
{
    constexpr int NB  = 128;
    constexpr int NQ  = K / 32;        // float4s per lane (full row)
    constexpr int NPH = K / 64;        // k-half phases (1 or 2)
    constexpr int RSs = 72;            // meanS row stride in shorts (9 granules, odd)
    constexpr int PS  = NB * RSs;      // plane stride (shorts)

    __shared__ short meanS[2 * PS];    // 36,864 B (one k-half, hi+lo planes)
    __shared__ short Wbuf[20480];      // 40,960 B (two 32-k chunks)

    const int n0 = blockIdx.x * NB;
    const int t  = threadIdx.x;
    const int l  = t & 63;
    const int w  = t >> 6;
    const int rg = w & 3;              // row group: 32 nodes
    const int cg = w >> 2;             // col group: 64 cols
    const int q8 = (l >> 4) * 8;       // k-quarter offset in shorts

    // gather mapping: 64 teams of 8 lanes; team handles nodes {team, team+64}
    const int team  = t >> 3;
    const int lane8 = t & 7;

    f32x4 acc[2][4];
    #pragma unroll
    for (int ct = 0; ct < 4; ++ct) {
        const float b = bias[cg * 64 + ct * 16 + (l & 15)];
        #pragma unroll
        for (int rt = 0; rt < 2; ++rt) acc[rt][ct] = (f32x4){b, b, b, b};
    }

    for (int rr = 0; rr <= NREL; ++rr) {
        __syncthreads();   // prev relation done reading meanS/Wbuf

        const short* wtRel = Wt + (size_t)rr * (2 * NPH) * 10240;

        // stage W chunks {0,1} (k 0..63); lands under the gather
        stage40(wtRel, Wbuf, t, 40960);

        // ---- fused dual-node branchless gather: full-K sums in registers ----
        const int nA = n0 + team;
        const int nB = n0 + team + 64;
        float sAx[NQ], sAy[NQ], sAz[NQ], sAw[NQ];
        float sBx[NQ], sBy[NQ], sBz[NQ], sBw[NQ];
        #pragma unroll
        for (int q = 0; q < NQ; ++q) {
            sAx[q] = sAy[q] = sAz[q] = sAw[q] = 0.f;
            sBx[q] = sBy[q] = sBz[q] = sBw[q] = 0.f;
        }
        float invA = 1.0f, invB = 1.0f;

        if (rr < NREL) {
            int cA = 0, oA = 0, cB = 0, oB = 0;
            if (nA < nnodes) { const int sg = nA * NREL + rr; cA = cnt[sg]; oA = off[sg] - cA; }
            if (nB < nnodes) { const int sg = nB * NREL + rr; cB = cnt[sg]; oB = off[sg] - cB; }
            const int jmax = max(cA, cB);
            for (int j = 0; j < jmax; ++j) {
                const bool pa = j < cA, pb = j < cB;
                const int ia = csr_src[pa ? (oA + j) : 0];   // safe clamped address
                const int ib = csr_src[pb ? (oB + j) : 0];
                const float* pxA = X + (size_t)ia * K;
                const float* pxB = X + (size_t)ib * K;
                float4 vA[NQ], vB[NQ];
                #pragma unroll
                for (int q = 0; q < NQ; ++q) vA[q] = *(const float4*)&pxA[q * 32 + lane8 * 4];
                #pragma unroll
                for (int q = 0; q < NQ; ++q) vB[q] = *(const float4*)&pxB[q * 32 + lane8 * 4];
                if (pa) {
                    #pragma unroll
                    for (int q = 0; q < NQ; ++q) {
                        sAx[q] += vA[q].x; sAy[q] += vA[q].y; sAz[q] += vA[q].z; sAw[q] += vA[q].w;
                    }
                }
                if (pb) {
                    #pragma unroll
                    for (int q = 0; q < NQ; ++q) {
                        sBx[q] += vB[q].x; sBy[q] += vB[q].y; sBz[q] += vB[q].z; sBw[q] += vB[q].w;
                    }
                }
            }
            invA = 1.0f / (float)max(cA, 1);
            invB = 1.0f / (float)max(cB, 1);
        } else {
            // root pseudo-relation: mean = own row
            if (nA < nnodes) {
                const float* xr = X + (size_t)nA * K;
                #pragma unroll
                for (int q = 0; q < NQ; ++q) {
                    const float4 v = *(const float4*)&xr[q * 32 + lane8 * 4];
                    sAx[q] = v.x; sAy[q] = v.y; sAz[q] = v.z; sAw[q] = v.w;
                }
            }
            if (nB < nnodes) {
                const float* xr = X + (size_t)nB * K;
                #pragma unroll
                for (int q = 0; q < NQ; ++q) {
                    const float4 v = *(const float4*)&xr[q * 32 + lane8 * 4];
                    sBx[q] = v.x; sBy[q] = v.y; sBz[q] = v.z; sBw[q] = v.w;
                }
            }
        }
        // apply mean division once (multiply; sums become final values)
        #pragma unroll
        for (int q = 0; q < NQ; ++q) {
            sAx[q] *= invA; sAy[q] *= invA; sAz[q] *= invA; sAw[q] *= invA;
            sBx[q] *= invB; sBy[q] *= invB; sBz[q] *= invB; sBw[q] *= invB;
        }

        // ---- k-half phases ----
        #pragma unroll
        for (int p = 0; p < NPH; ++p) {
            if (p == 1) {
                __syncthreads();                       // phase-0 GEMM done with Wbuf/meanS
                stage40(wtRel + 2 * 10240, Wbuf, t, 40960);   // chunks {2,3}
            }
            // write this k-half (hi,lo) planes
            #pragma unroll
            for (int qq = 0; qq < 2; ++qq) {
                const int qg = p * 2 + qq;
                const int kb = qq * 32 + lane8 * 4;
                {
                    const float vx = sAx[qg], vy = sAy[qg], vz = sAz[qg], vw = sAw[qg];
                    const unsigned short hx = bf16rn(vx), hy = bf16rn(vy), hz = bf16rn(vz), hw = bf16rn(vw);
                    short4 hi4, lo4;
                    hi4.x = (short)hx; hi4.y = (short)hy; hi4.z = (short)hz; hi4.w = (short)hw;
                    lo4.x = (short)bf16rn(vx - bf16tof(hx));
                    lo4.y = (short)bf16rn(vy - bf16tof(hy));
                    lo4.z = (short)bf16rn(vz - bf16tof(hz));
                    lo4.w = (short)bf16rn(vw - bf16tof(hw));
                    *(short4*)&meanS[team * RSs + kb]      = hi4;
                    *(short4*)&meanS[PS + team * RSs + kb] = lo4;
                }
                {
                    const float vx = sBx[qg], vy = sBy[qg], vz = sBz[qg], vw = sBw[qg];
                    const unsigned short hx = bf16rn(vx), hy = bf16rn(vy), hz = bf16rn(vz), hw = bf16rn(vw);
                    short4 hi4, lo4;
                    hi4.x = (short)hx; hi4.y = (short)hy; hi4.z = (short)hz; hi4.w = (short)hw;
                    lo4.x = (short)bf16rn(vx - bf16tof(hx));
                    lo4.y = (short)bf16rn(vy - bf16tof(hy));
                    lo4.z = (short)bf16rn(vz - bf16tof(hz));
                    lo4.w = (short)bf16rn(vw - bf16tof(hw));
                    *(short4*)&meanS[(team + 64) * RSs + kb]      = hi4;
                    *(short4*)&meanS[PS + (team + 64) * RSs + kb] = lo4;
                }
            }

            __syncthreads();   // drains vmcnt (Wbuf landed) + lgkm (meanS visible)

            // ---- GEMM this k-half: 3-product bf16 split MFMA ----
            #pragma unroll
            for (int ls = 0; ls < 2; ++ls) {
                short8 bf[4][2];
                #pragma unroll
                for (int ct = 0; ct < 4; ++ct) {
                    const int col = cg * 64 + ct * 16 + (l & 15);
                    bf[ct][0] = *(const short8*)&Wbuf[ls * 10240 +        col * 40 + q8];
                    bf[ct][1] = *(const short8*)&Wbuf[ls * 10240 + 5120 + col * 40 + q8];
                }
                #pragma unroll
                for (int rt = 0; rt < 2; ++rt) {
                    const int row = rg * 32 + rt * 16 + (l & 15);
                    const int ka  = row * RSs + ls * 32 + q8;
                    const short8 a0 = *(const short8*)&meanS[ka];
                    const short8 a1 = *(const short8*)&meanS[PS + ka];
                    #pragma unroll
                    for (int ct = 0; ct < 4; ++ct) {
                        acc[rt][ct] = __builtin_amdgcn_mfma_f32_16x16x32_bf16(a0, bf[ct][0], acc[rt][ct], 0, 0, 0);
                        acc[rt][ct] = __builtin_amdgcn_mfma_f32_16x16x32_bf16(a0, bf[ct][1], acc[rt][ct], 0, 0, 0);
                        acc[rt][ct] = __builtin_amdgcn_mfma_f32_16x16x32_bf16(a1, bf[ct][0], acc[rt][ct], 0, 0, 0);
                    }
                }
            }
        }
    }

    // ---- write H: D layout col=lane&15, row=(lane>>4)*4+reg ----
    #pragma unroll
    for (int rt = 0; rt < 2; ++rt) {
        #pragma unroll
        for (int reg = 0; reg < 4; ++reg) {
            const int node = n0 + rg * 32 + rt * 16 + (l >> 4) * 4 + reg;
            if (node < nnodes) {
                #pragma unroll
                for (int ct = 0; ct < 4; ++ct) {
                    float v = acc[rt][ct][reg];
                    if (RELU) v = fmaxf(v, 0.0f);
                    H[(size_t)node * 128 + cg * 64 + ct * 16 + (l & 15)] = v;
                }
            }
        }
    }
}

// ---------------------------------------------------------------------------
// DistMult decoder: one 64-lane wave per batch element
// ---------------------------------------------------------------------------
__global__ void decoder_kernel(const float* __restrict__ H, const float* __restrict__ rel_emb,
                               const int* __restrict__ head, const int* __restrict__ tail,
                               const int* __restrict__ rt, float* __restrict__ out, int B) {
    const int idx  = blockIdx.x * blockDim.x + threadIdx.x;
    const int b    = idx >> 6;
    const int lane = idx & 63;
    if (b >= B) return;
    const float* hp = H + (size_t)head[b] * 128;
    const float* tp = H + (size_t)tail[b] * 128;
    const float* rp = rel_emb + (size_t)rt[b] * 128;
    double s = 0.0;
    #pragma unroll
    for (int c = 0; c < 2; ++c) {
        const int k = lane + c * 64;
        s += (double)hp[k] * (double)rp[k] * (double)tp[k];
    }
    for (int o = 32; o > 0; o >>= 1) s += __shfl_down(s, o);
    if (lane == 0) out[b] = (float)s;
}

// ---------------------------------------------------------------------------

extern "C" void kernel_launch(void* const* d_in, const int* in_sizes, int n_in,
                              void* d_out, int out_size, void* d_ws, size_t ws_size,
                              hipStream_t stream) {
    const int*   edge_index = (const int*)d_in[0];   // [2][E]
    const int*   edge_type  = (const int*)d_in[1];   // [E]
    const int*   head       = (const int*)d_in[2];   // [B]
    const int*   tail       = (const int*)d_in[3];   // [B]
    const int*   rtyp       = (const int*)d_in[4];   // [B]
    const float* node_emb   = (const float*)d_in[5]; // [N][64]
    const float* W1         = (const float*)d_in[6]; // [20][64][128]
    const float* root1      = (const float*)d_in[7]; // [64][128]
    const float* b1         = (const float*)d_in[8]; // [128]
    const float* W2         = (const float*)d_in[9]; // [20][128][128]
    const float* root2      = (const float*)d_in[10];// [128][128]
    const float* b2         = (const float*)d_in[11];// [128]
    const float* rel_emb    = (const float*)d_in[12];// [20][128]
    float* out = (float*)d_out;

    const int E = in_sizes[1];
    const int B = in_sizes[2];
    const int* src = edge_index;
    const int* dst = edge_index + E;

    // workspace carve (all 256B-aligned)
    char* ws = (char*)d_ws;
    size_t o = 0;
    auto carve = [&](size_t bytes) { char* p = ws + o; o += (bytes + 255) & ~size_t(255); return p; };
    int*   off     = (int*)carve(sizeof(int) * NSEG);        // 4 MB
    int*   cnt     = (int*)carve(sizeof(int) * NSEG);        // 4 MB
    int*   csr_src = (int*)carve(sizeof(int) * (size_t)E);   // 6.4 MB
    int*   bsum    = (int*)carve(sizeof(int) * 1024);
    float* h1      = (float*)carve(sizeof(float) * (size_t)NNODES * DHID); // 25.6 MB
    float* h2      = (float*)carve(sizeof(float) * (size_t)NNODES * DHID); // 25.6 MB
    short* Wt1     = (short*)carve(sizeof(short) * (size_t)(NREL + 1) * 2 * 10240); // 1.72 MB
    short* Wt2     = (short*)carve(sizeof(short) * (size_t)(NREL + 1) * 4 * 10240); // 3.44 MB
    (void)ws_size;

    const int NCHUNK = (NSEG + 1023) / 1024;   // 977

    // W prep (independent of CSR; cheap)
    {
        const int tot1 = (NREL + 1) * 128 * DEMB;
        const int tot2 = (NREL + 1) * 128 * DHID;
        prep_w<DEMB><<<(tot1 + 255) / 256, 256, 0, stream>>>(W1, root1, Wt1);
        prep_w<DHID><<<(tot2 + 255) / 256, 256, 0, stream>>>(W2, root2, Wt2);
    }

    // CSR build
    hipMemsetAsync(cnt, 0, sizeof(int) * NSEG, stream);
    hist_kernel<<<2048, 256, 0, stream>>>(dst, edge_type, E, cnt);
    scan_partial<<<NCHUNK, 256, 0, stream>>>(cnt, bsum, NSEG);
    scan_bsums<<<1, 1024, 0, stream>>>(bsum, NCHUNK);
    scan_final<<<NCHUNK, 256, 0, stream>>>(cnt, bsum, off, NSEG);
    place_kernel<<<2048, 256, 0, stream>>>(src, dst, edge_type, E, off, csr_src);

    // layers (128 nodes per block, 512 threads)
    const int LBLK = (NNODES + 127) / 128;   // 391
    rgcn_layer_kernel<DEMB, true ><<<LBLK, 512, 0, stream>>>(node_emb, Wt1, b1,
                                                             off, cnt, csr_src, h1, NNODES);
    rgcn_layer_kernel<DHID, false><<<LBLK, 512, 0, stream>>>(h1, Wt2, b2,
                                                             off, cnt, csr_src, h2, NNODES);

    // decoder
    decoder_kernel<<<(B * 64 + 255) / 256, 256, 0, stream>>>(h2, rel_emb, head, tail, rtyp, out, B);
}